// Round 21
// baseline (96.724 us; speedup 1.0000x reference)
//
#include <hip/hip_runtime.h>
#include <cstdint>
#include <cstddef>

// ---------- types ----------
typedef __attribute__((ext_vector_type(8))) __bf16 bf16x8;
typedef __attribute__((ext_vector_type(4))) float f32x4;

// fp32 -> bf16 round-to-nearest-even
__device__ __forceinline__ unsigned short f2bf(float x) {
    unsigned int u = __float_as_uint(x);
    u += 0x7fffu + ((u >> 16) & 1u);
    return (unsigned short)(u >> 16);
}

__device__ __forceinline__ ushort4 pack4bf(float a, float b, float c, float d) {
    union { ushort4 v; __bf16 e[4]; } u;
    u.e[0] = (__bf16)a; u.e[1] = (__bf16)b; u.e[2] = (__bf16)c; u.e[3] = (__bf16)d;
    return u.v;
}

// raw v_exp_f32 (single TRANS op) instead of guarded OCML exp2f
#if defined(__has_builtin)
#if __has_builtin(__builtin_amdgcn_exp2f)
#define EXP2(x) __builtin_amdgcn_exp2f(x)
#else
#define EXP2(x) exp2f(x)
#endif
#else
#define EXP2(x) exp2f(x)
#endif

typedef const __attribute__((address_space(1))) void* gptr_t;
typedef __attribute__((address_space(3))) void* lptr_t;
__device__ __forceinline__ void gload_lds16(const void* g, void* l) {
    __builtin_amdgcn_global_load_lds((gptr_t)g, (lptr_t)l, 16, 0, 0);
}

// ---------- prologue: transpose+cast the 4 weight matrices ----------
// grid 1024 = 16x16 tiles x 4 matrices, 64x64 tiles via LDS.
__global__ __launch_bounds__(256) void prologue_kernel(const float* __restrict__ W0,
                                                       const float* __restrict__ W1,
                                                       const float* __restrict__ W2,
                                                       const float* __restrict__ W3,
                                                       unsigned short* __restrict__ T0,
                                                       unsigned short* __restrict__ T1,
                                                       unsigned short* __restrict__ T2,
                                                       unsigned short* __restrict__ T3,
                                                       float s0) {
    __shared__ float Ts[64][65];
    const int D = 1024;
    const int tid = threadIdx.x;
    const int bid = blockIdx.x;                   // 0..1023
    const int m = bid >> 8;                       // matrix 0..3
    const int t2 = bid & 255;                     // 16x16 tiles
    const float* W = (m == 0) ? W0 : (m == 1) ? W1 : (m == 2) ? W2 : W3;
    unsigned short* T = (m == 0) ? T0 : (m == 1) ? T1 : (m == 2) ? T2 : T3;
    const float scale = (m == 0) ? s0 : 1.0f;
    const int kt = (t2 >> 4) * 64, nt = (t2 & 15) * 64;

    {
        const int r = tid >> 2, cs = (tid & 3) * 16;
#pragma unroll
        for (int j = 0; j < 16; j += 4) {
            f32x4 v = *(const f32x4*)&W[(size_t)(kt + r) * D + nt + cs + j];
#pragma unroll
            for (int e = 0; e < 4; ++e) Ts[r][cs + j + e] = v[e];
        }
    }
    __syncthreads();
    {
        const int n = tid >> 2, ks = (tid & 3) * 16;
        union { bf16x8 v[2]; __bf16 e[16]; } cv;
#pragma unroll
        for (int j = 0; j < 16; ++j) cv.e[j] = (__bf16)(Ts[ks + j][n] * scale);
        *(bf16x8*)&T[(size_t)(nt + n) * D + kt + ks] = cv.v[0];
        *(bf16x8*)&T[(size_t)(nt + n) * D + kt + ks + 8] = cv.v[1];
    }
}

// ---------- GEMM, C = A * B with Bt = B^T given ----------
// 128 x (NBF*32) tile, BK=BKT, 4 waves (2x2), XOR-pre-swizzled LDS
// (chunk c_src = c ^ (row&7); frag reads same XOR -> conflict-free).
// AF32=1: A is fp32, reg-staged (coalesced f32x4 loads at the pre-swizzled
// source column, native cvt to bf16, ds_write_b128 to the LINEAR chunk) —
// produces a byte-identical LDS image to the global_load_lds path, and the
// next tile's A-regs prefetch under the MFMAs. Fuses the x-cast into the GEMM.
// VT=1 (NBF=4): V-projection blocks (n0>=2048) write transposed to Vt.
template <int AF32, int OUTBF, int VT, int NBF, int BKT>
__global__ __launch_bounds__(256) void gemm_bt(const void* __restrict__ Ain,
                                               const unsigned short* __restrict__ Bt,
                                               void* __restrict__ Cout,
                                               unsigned short* __restrict__ Vt,
                                               int M, int N, int K, int lda, int ldc,
                                               int nbx) {
    static_assert(!VT || NBF == 4, "VT path requires NBF=4");
    static_assert(!AF32 || BKT == 64, "AF32 path implemented for BKT=64");
    __shared__ __align__(16) unsigned short Au[128 * BKT];
    __shared__ __align__(16) unsigned short Bs[NBF * 32 * BKT];
    const int tid = threadIdx.x;
    const int w = tid >> 6;
    const int lane = tid & 63;

    const int nwg = gridDim.x;
    const int q8 = nwg >> 3;
    const int orig = blockIdx.x;
    const int newlin = (orig & 7) * q8 + (orig >> 3);
    const int by = newlin / nbx;
    const int bx = newlin - by * nbx;
    const int m0 = by * 128;
    const int n0 = bx * (NBF * 32);
    const int wr = w >> 1, wc = w & 1;

    f32x4 acc[4][NBF];
#pragma unroll
    for (int i = 0; i < 4; ++i)
#pragma unroll
        for (int j = 0; j < NBF; ++j) acc[i][j] = f32x4{0.f, 0.f, 0.f, 0.f};

    constexpr int CPR = BKT / 8;        // 16B chunks per row
    constexpr int RP = 256 / CPR;       // rows covered per 256-thread pass
    const int srow = tid / CPR;         // row within pass
    const int sch = (tid % CPR) ^ (srow & 7);   // pre-swizzled source chunk

    const int fq = lane & 15, fg = lane >> 4;

    const float* A32 = (const float*)Ain;
    const unsigned short* A16 = (const unsigned short*)Ain;
    f32x4 ar[4][2];
    if (AF32) {
#pragma unroll
        for (int p = 0; p < 4; ++p) {
            const float* s = A32 + (size_t)(m0 + p * 32 + srow) * lda + sch * 8;
            ar[p][0] = *(const f32x4*)s;
            ar[p][1] = *(const f32x4*)(s + 4);
        }
    }

    for (int kt = 0; kt < K; kt += BKT) {
        // ---- stage A tile ----
        if (AF32) {
#pragma unroll
            for (int p = 0; p < 4; ++p) {
                union { bf16x8 v; __bf16 e[8]; } cv;
#pragma unroll
                for (int j = 0; j < 8; ++j) cv.e[j] = (__bf16)ar[p][j >> 2][j & 3];
                *(bf16x8*)&Au[(size_t)(p * 256 + tid) * 8] = cv.v;
            }
        } else {
#pragma unroll
            for (int p = 0; p < 128 / RP; ++p)
                gload_lds16(A16 + (size_t)(m0 + p * RP + srow) * lda + kt + sch * 8,
                            &Au[(p * 256 + w * 64) * 8]);
        }
        // ---- stage Bt tile ----
#pragma unroll
        for (int p = 0; p < NBF * 32 / RP; ++p)
            gload_lds16(Bt + (size_t)(n0 + p * RP + srow) * K + kt + sch * 8,
                        &Bs[(p * 256 + w * 64) * 8]);
        __syncthreads();

        // ---- prefetch next A tile into registers (hides under MFMA) ----
        if (AF32 && kt + BKT < K) {
#pragma unroll
            for (int p = 0; p < 4; ++p) {
                const float* s = A32 + (size_t)(m0 + p * 32 + srow) * lda + kt + BKT + sch * 8;
                ar[p][0] = *(const f32x4*)s;
                ar[p][1] = *(const f32x4*)(s + 4);
            }
        }

        bf16x8 af[4], bfr[NBF];
#pragma unroll
        for (int sub = 0; sub < BKT / 32; ++sub) {
            const int xa = (((sub * 4 + fg) ^ (fq & 7)) << 3);
#pragma unroll
            for (int m = 0; m < 4; ++m)
                af[m] = *(const bf16x8*)&Au[(wr * 64 + m * 16 + fq) * BKT + xa];
#pragma unroll
            for (int n = 0; n < NBF; ++n)
                bfr[n] = *(const bf16x8*)&Bs[(wc * (NBF * 16) + n * 16 + fq) * BKT + xa];
#pragma unroll
            for (int m = 0; m < 4; ++m)
#pragma unroll
                for (int n = 0; n < NBF; ++n)
                    acc[m][n] = __builtin_amdgcn_mfma_f32_16x16x32_bf16(af[m], bfr[n], acc[m][n], 0, 0, 0);
        }
        __syncthreads();
    }

    const int crow = (lane >> 4) * 4;
    const int ccol = lane & 15;

    if constexpr (VT) {
        if (n0 >= 2048) {
            __shared__ __align__(16) unsigned short Tw[4][32 * 72];
            const int bb = m0 >> 11;
            const int h = ((n0 - 2048) >> 6) + wc;
            const int kvbase = (m0 & 2047) + wr * 64;
            unsigned short* vdst = Vt + (size_t)((bb * 16 + h) * 64) * 2048 + kvbase;
#pragma unroll
            for (int pass = 0; pass < 2; ++pass) {
#pragma unroll
                for (int m = 0; m < 4; ++m)
#pragma unroll
                    for (int nn = 0; nn < 2; ++nn) {
                        int n = pass * 2 + nn;
                        int c = nn * 16 + ccol;
                        *(ushort4*)&Tw[w][c * 72 + m * 16 + crow] =
                            pack4bf(acc[m][n][0], acc[m][n][1], acc[m][n][2], acc[m][n][3]);
                    }
                asm volatile("" ::: "memory");
                const int d_loc = lane >> 1;
                const int kvh = (lane & 1) * 32;
                unsigned short* dst = vdst + (size_t)(pass * 32 + d_loc) * 2048 + kvh;
#pragma unroll
                for (int i = 0; i < 4; ++i) {
                    bf16x8 v = *(const bf16x8*)&Tw[w][d_loc * 72 + kvh + i * 8];
                    *(bf16x8*)&dst[i * 8] = v;
                }
                asm volatile("" ::: "memory");
            }
            return;
        }
    }

#pragma unroll
    for (int m = 0; m < 4; ++m) {
#pragma unroll
        for (int n = 0; n < NBF; ++n) {
            int r0 = m0 + wr * 64 + m * 16 + crow;
            int c0 = n0 + wc * (NBF * 16) + n * 16 + ccol;
#pragma unroll
            for (int j = 0; j < 4; ++j) {
                if (OUTBF)
                    ((unsigned short*)Cout)[(size_t)(r0 + j) * ldc + c0] = f2bf(acc[m][n][j]);
                else
                    ((float*)Cout)[(size_t)(r0 + j) * ldc + c0] = acc[m][n][j];
            }
        }
    }
}

// ---------- causal flash attention (rotated pipeline, ping-pong unroll) ----------
// QKV fused [B*L, 3072] bf16: Q cols [0,1024), K [1024,2048).
// Vt [bh][d=64][kv=2048]. Q pre-scaled by log2(e)/sqrt(hd). O in-place over Q.
// Grid (32 bh, 32 y): linear%8 = bh%8; y -> qblk 31-y (heavy-first, measured).
// K/V^T staged via global_load_lds, XOR-pre-swizzled source (c^=row&7);
// reads x0/x1 same XOR -> conflict-free.
// Rotated pipeline with 2x PING-PONG UNROLL (no sprev=snew copies).
// Diagonal masking only in the (parity-branched) epilogue SM.
__global__ __launch_bounds__(256) void flash_kernel(unsigned short* __restrict__ QKV,
                                                    const unsigned short* __restrict__ Vt) {
    __shared__ __align__(16) unsigned short Ks[2][64 * 64];
    __shared__ __align__(16) unsigned short Vs[64 * 64];
    __shared__ __align__(16) unsigned short Ps[4][16 * 72];

    const int tid = threadIdx.x;
    const int w = tid >> 6;
    const int lane = tid & 63;
    const int bh = blockIdx.x;          // XCD = bh % 8
    const int b = bh >> 4, h = bh & 15;
    const int rowbase = b * 2048;
    const int hd0 = h * 64;
    const int S = 3072;

    const int qi = lane & 15;           // lane's q column (softmax space)
    const int g = lane >> 4;            // lane group
    const int x0 = ((g ^ (qi & 7)) << 3);
    const int x1 = (((g ^ 4) ^ (qi & 7)) << 3);

    const int qblk = (31 - (int)blockIdx.y) * 64;
    const int q0 = qblk + w * 16;
    const int nt = qblk / 64 + 1;
    const int q_rel = w * 16 + qi;

    const unsigned short* gK[2];
    const unsigned short* gV[2];
#pragma unroll
    for (int p = 0; p < 2; ++p) {
        int row = p * 32 + w * 8 + (lane >> 3);       // kv for K, d for V
        int ch = (lane & 7) ^ (row & 7);
        gK[p] = QKV + (size_t)(rowbase + row) * S + 1024 + hd0 + ch * 8;
        gV[p] = Vt + (size_t)(bh * 64 + row) * 2048 + ch * 8;
    }

#define STAGE_K(buf)                                            \
    do {                                                        \
        gload_lds16(gK[0], &Ks[buf][w * 512]);                  \
        gload_lds16(gK[1], &Ks[buf][2048 + w * 512]);           \
        gK[0] += 64 * S; gK[1] += 64 * S;                       \
    } while (0)
#define STAGE_V()                                               \
    do {                                                        \
        gload_lds16(gV[0], &Vs[w * 512]);                       \
        gload_lds16(gV[1], &Vs[2048 + w * 512]);                \
        gV[0] += 64; gV[1] += 64;                               \
    } while (0)

    bf16x8 qf[2];
#pragma unroll
    for (int st = 0; st < 2; ++st)
        qf[st] = *(const bf16x8*)(QKV + (size_t)(rowbase + q0 + qi) * S + hd0 +
                                  st * 32 + g * 8);

    float m_prev = -1e30f, lsum = 0.f;   // per-lane partials (16 kv cols)
    f32x4 oacc[4];
#pragma unroll
    for (int n = 0; n < 4; ++n) oacc[n] = f32x4{0.f, 0.f, 0.f, 0.f};
    f32x4 sA[4], sB[4];

    STAGE_K(0);
    if (nt > 1) STAGE_K(1);
    __syncthreads();   // drains K(0), K(1)

    // QKT of tile (reads Ks[KB]) into SP
#define QKT(SP, KB)                                                            \
    do {                                                                       \
        const unsigned short* Kc = Ks[KB];                                     \
        __builtin_amdgcn_s_setprio(1);                                         \
        _Pragma("unroll")                                                      \
        for (int n = 0; n < 4; ++n) {                                          \
            bf16x8 k0 = *(const bf16x8*)&Kc[(n * 16 + qi) * 64 + x0];          \
            bf16x8 k1 = *(const bf16x8*)&Kc[(n * 16 + qi) * 64 + x1];          \
            f32x4 c = f32x4{0.f, 0.f, 0.f, 0.f};                               \
            c = __builtin_amdgcn_mfma_f32_16x16x32_bf16(k0, qf[0], c, 0, 0, 0);\
            c = __builtin_amdgcn_mfma_f32_16x16x32_bf16(k1, qf[1], c, 0, 0, 0);\
            SP[n] = c;                                                         \
        }                                                                      \
        __builtin_amdgcn_s_setprio(0);                                         \
    } while (0)

    // softmax on SP (no masking) -> Ps, lsum, oacc rescale
#define SOFTMAX(SP)                                                            \
    do {                                                                       \
        float tmax = m_prev;                                                   \
        _Pragma("unroll")                                                      \
        for (int n = 0; n < 4; ++n) {                                          \
            tmax = fmaxf(fmaxf(tmax, SP[n][0]), SP[n][1]);                     \
            tmax = fmaxf(fmaxf(tmax, SP[n][2]), SP[n][3]);                     \
        }                                                                      \
        const bool defer = __all(tmax - m_prev <= 8.0f);                       \
        float mcur = m_prev;                                                   \
        if (!defer) {                                                          \
            tmax = fmaxf(tmax, __shfl_xor(tmax, 16));                          \
            tmax = fmaxf(tmax, __shfl_xor(tmax, 32));                          \
            mcur = tmax;                                                       \
            float alpha = EXP2(m_prev - mcur);                                 \
            lsum *= alpha;                                                     \
            _Pragma("unroll")                                                  \
            for (int n = 0; n < 4; ++n)                                        \
                _Pragma("unroll")                                              \
                for (int j = 0; j < 4; ++j) oacc[n][j] *= alpha;               \
            m_prev = mcur;                                                     \
        }                                                                      \
        float psum = 0.f;                                                      \
        _Pragma("unroll")                                                      \
        for (int n = 0; n < 4; ++n) {                                          \
            float p0 = EXP2(SP[n][0] - mcur);                                  \
            float p1 = EXP2(SP[n][1] - mcur);                                  \
            float p2 = EXP2(SP[n][2] - mcur);                                  \
            float p3 = EXP2(SP[n][3] - mcur);                                  \
            psum += (p0 + p1) + (p2 + p3);                                     \
            *(ushort4*)&Ps[w][qi * 72 + n * 16 + g * 4] = pack4bf(p0, p1, p2, p3); \
        }                                                                      \
        lsum += psum;                                                          \
    } while (0)

#define PV_STEP()                                                              \
    do {                                                                       \
        __builtin_amdgcn_s_setprio(1);                                         \
        _Pragma("unroll")                                                      \
        for (int st = 0; st < 2; ++st) {                                       \
            bf16x8 ptf = *(const bf16x8*)&Ps[w][qi * 72 + st * 32 + g * 8];    \
            const int xo = st ? x1 : x0;                                       \
            _Pragma("unroll")                                                  \
            for (int n = 0; n < 4; ++n) {                                      \
                bf16x8 vfr = *(const bf16x8*)&Vs[(n * 16 + qi) * 64 + xo];     \
                oacc[n] = __builtin_amdgcn_mfma_f32_16x16x32_bf16(vfr, ptf, oacc[n], 0, 0, 0); \
            }                                                                  \
        }                                                                      \
        __builtin_amdgcn_s_setprio(0);                                         \
    } while (0)

    // full iteration for tile T>0: QKT(T)->SNEW, SM+PV of tile T-1 on SOLD
#define ITER(T, SNEW, SOLD, KB)                                                \
    do {                                                                       \
        QKT(SNEW, KB);                                                         \
        SOFTMAX(SOLD);                                                         \
        __syncthreads();  /* barA: V(T-1) landed */                            \
        PV_STEP();        /* PV(T-1) on Vs */                                  \
        __syncthreads();  /* barB: Vs reads done */                            \
        STAGE_V();        /* V(T) -> Vs */                                     \
        if ((T) + 2 < nt) STAGE_K(KB);                                         \
    } while (0)

    // ---- tile 0 (no SM/PV yet): t even -> sA ----
    QKT(sA, 0);
    __syncthreads();                 // barA (uniform barrier count)
    __syncthreads();                 // barB: QKT(0) reads retired before DMA
    STAGE_V();                       // V(0)
    if (2 < nt) STAGE_K(0);          // K(2)

    // ---- ping-pong pairs: t odd uses (sB <- QKT, SM on sA), t even mirrored ----
    int t = 1;
    for (; t + 1 < nt; t += 2) {
        ITER(t, sB, sA, 1);
        ITER(t + 1, sA, sB, 0);
    }
    if (t < nt) ITER(t, sB, sA, 1);  // leftover t is odd

    // ---- epilogue: diagonal masking + SM + PV for tile nt-1 (parity branch) ----
    __syncthreads();   // drains V(nt-1)
    if ((nt - 1) & 1) {
#pragma unroll
        for (int n = 0; n < 4; ++n)
#pragma unroll
            for (int j = 0; j < 4; ++j)
                if (n * 16 + g * 4 + j > q_rel) sB[n][j] = -1e30f;
        SOFTMAX(sB);
    } else {
#pragma unroll
        for (int n = 0; n < 4; ++n)
#pragma unroll
            for (int j = 0; j < 4; ++j)
                if (n * 16 + g * 4 + j > q_rel) sA[n][j] = -1e30f;
        SOFTMAX(sA);
    }
    asm volatile("" ::: "memory");
    PV_STEP();
#undef QKT
#undef SOFTMAX
#undef PV_STEP
#undef ITER
#undef STAGE_K
#undef STAGE_V

    // ---- reduce lsum across the column group, normalize, write O ----
    {
        lsum += __shfl_xor(lsum, 16);
        lsum += __shfl_xor(lsum, 32);
        float inv = 1.0f / lsum;
#pragma unroll
        for (int n = 0; n < 4; ++n)
            *(ushort4*)&Ps[w][qi * 72 + n * 16 + g * 4] =
                pack4bf(oacc[n][0] * inv, oacc[n][1] * inv, oacc[n][2] * inv, oacc[n][3] * inv);
        asm volatile("" ::: "memory");
        const int r = lane >> 2;
        const int cs = (lane & 3) * 16;
        bf16x8 o0 = *(const bf16x8*)&Ps[w][r * 72 + cs];
        bf16x8 o1 = *(const bf16x8*)&Ps[w][r * 72 + cs + 8];
        *(bf16x8*)&QKV[(size_t)(rowbase + q0 + r) * S + hd0 + cs] = o0;
        *(bf16x8*)&QKV[(size_t)(rowbase + q0 + r) * S + hd0 + cs + 8] = o1;
    }
}

// ---------- launch ----------
extern "C" void kernel_launch(void* const* d_in, const int* in_sizes, int n_in,
                              void* d_out, int out_size, void* d_ws, size_t ws_size,
                              hipStream_t stream) {
    const float* x  = (const float*)d_in[0];
    const float* Wq = (const float*)d_in[1];
    const float* Wk = (const float*)d_in[2];
    const float* Wv = (const float*)d_in[3];
    const float* Wo = (const float*)d_in[4];
    float* out = (float*)d_out;

    const int WN = 1024 * 1024;

    // ws (32MB): Wqkv_t (6MB) + Wo_t (2MB) + QKV [4096][3072] (24MB).
    // d_out (16MB) doubles as scratch: Vt (8MB) in its front half — dead
    // before the final O-projection overwrites d_out. Deterministic.
    unsigned short* ws   = (unsigned short*)d_ws;
    unsigned short* Wqkv = ws;
    unsigned short* Wot  = Wqkv + 3 * WN;
    unsigned short* QKV  = Wot + WN;
    unsigned short* Vt   = (unsigned short*)d_out;

    // prologue: weight transposes only (Q scale folds 1/sqrt(hd)*log2e)
    prologue_kernel<<<1024, 256, 0, stream>>>(
        Wq, Wk, Wv, Wo,
        Wqkv, Wqkv + WN, Wqkv + 2 * WN, Wot, 0.125f * 1.4426950408889634f);

    // fused QKV projection: x (fp32, reg-staged cast) x Wqkv^T -> QKV;
    // V-blocks write transposed into Vt (fused vtrans). BK=64.
    gemm_bt<1, 1, 1, 4, 64><<<24 * 32, 256, 0, stream>>>(
        x, Wqkv, QKV, Vt, 4096, 3072, 1024, 1024, 3072, 24);

    flash_kernel<<<dim3(32, 32), 256, 0, stream>>>(QKV, Vt);

    // output projection: A = O (bf16, Q region of QKV, lda=3072), BN=64, BK=128.
    gemm_bt<0, 0, 0, 2, 128><<<16 * 32, 256, 0, stream>>>(
        QKV, Wot, out, nullptr, 4096, 1024, 1024, 3072, 1024, 16);
}

// Round 22
// 95.491 us; speedup vs baseline: 1.0129x; 1.0129x over previous
//
#include <hip/hip_runtime.h>
#include <cstdint>
#include <cstddef>

// ---------- types ----------
typedef __attribute__((ext_vector_type(8))) __bf16 bf16x8;
typedef __attribute__((ext_vector_type(4))) float f32x4;

// fp32 -> bf16 round-to-nearest-even
__device__ __forceinline__ unsigned short f2bf(float x) {
    unsigned int u = __float_as_uint(x);
    u += 0x7fffu + ((u >> 16) & 1u);
    return (unsigned short)(u >> 16);
}

__device__ __forceinline__ ushort4 pack4bf(float a, float b, float c, float d) {
    union { ushort4 v; __bf16 e[4]; } u;
    u.e[0] = (__bf16)a; u.e[1] = (__bf16)b; u.e[2] = (__bf16)c; u.e[3] = (__bf16)d;
    return u.v;
}

// raw v_exp_f32 (single TRANS op) instead of guarded OCML exp2f
#if defined(__has_builtin)
#if __has_builtin(__builtin_amdgcn_exp2f)
#define EXP2(x) __builtin_amdgcn_exp2f(x)
#else
#define EXP2(x) exp2f(x)
#endif
#else
#define EXP2(x) exp2f(x)
#endif

typedef const __attribute__((address_space(1))) void* gptr_t;
typedef __attribute__((address_space(3))) void* lptr_t;
__device__ __forceinline__ void gload_lds16(const void* g, void* l) {
    __builtin_amdgcn_global_load_lds((gptr_t)g, (lptr_t)l, 16, 0, 0);
}

// ---------- fused prologue: cast x -> bf16 AND transpose+cast 4 weights ----------
__global__ __launch_bounds__(256) void prologue_kernel(const float* __restrict__ x,
                                                       unsigned short* __restrict__ xout,
                                                       const float* __restrict__ W0,
                                                       const float* __restrict__ W1,
                                                       const float* __restrict__ W2,
                                                       const float* __restrict__ W3,
                                                       unsigned short* __restrict__ T0,
                                                       unsigned short* __restrict__ T1,
                                                       unsigned short* __restrict__ T2,
                                                       unsigned short* __restrict__ T3,
                                                       float s0) {
    const int tid = threadIdx.x;
    if (blockIdx.x < 4096) {
        int i = blockIdx.x * 256 + tid;
        float4 v = ((const float4*)x)[i];
        ushort4 o;
        o.x = f2bf(v.x); o.y = f2bf(v.y); o.z = f2bf(v.z); o.w = f2bf(v.w);
        ((ushort4*)xout)[i] = o;
        return;
    }
    __shared__ float Ts[64][65];
    const int D = 1024;
    const int bid = blockIdx.x - 4096;            // 0..1023
    const int m = bid >> 8;                       // matrix 0..3
    const int t2 = bid & 255;                     // 16x16 tiles
    const float* W = (m == 0) ? W0 : (m == 1) ? W1 : (m == 2) ? W2 : W3;
    unsigned short* T = (m == 0) ? T0 : (m == 1) ? T1 : (m == 2) ? T2 : T3;
    const float scale = (m == 0) ? s0 : 1.0f;
    const int kt = (t2 >> 4) * 64, nt = (t2 & 15) * 64;

    {
        const int r = tid >> 2, cs = (tid & 3) * 16;
#pragma unroll
        for (int j = 0; j < 16; j += 4) {
            f32x4 v = *(const f32x4*)&W[(size_t)(kt + r) * D + nt + cs + j];
#pragma unroll
            for (int e = 0; e < 4; ++e) Ts[r][cs + j + e] = v[e];
        }
    }
    __syncthreads();
    {
        const int n = tid >> 2, ks = (tid & 3) * 16;
        union { bf16x8 v[2]; __bf16 e[16]; } cv;
#pragma unroll
        for (int j = 0; j < 16; ++j) cv.e[j] = (__bf16)(Ts[ks + j][n] * scale);
        *(bf16x8*)&T[(size_t)(nt + n) * D + kt + ks] = cv.v[0];
        *(bf16x8*)&T[(size_t)(nt + n) * D + kt + ks + 8] = cv.v[1];
    }
}

// ---------- GEMM, C = A * B with Bt = B^T given ----------
// 128 x (NBF*32) tile, BK=BKT (64 or 128), 4 waves (2x2), XOR-pre-swizzled LDS
// (chunk c_src = c ^ (row&7); frag reads same XOR -> conflict-free).
// 1D grid, bijective XCD-chunk swizzle. VT=1 (NBF=4 only): V-projection
// blocks (n0>=2048) write transposed to Vt via per-wave LDS transpose.
// BKT=128 halves barrier count (use where LDS/occupancy allows).
template <int OUTBF, int VT, int NBF, int BKT>
__global__ __launch_bounds__(256) void gemm_bt(const unsigned short* __restrict__ A,
                                               const unsigned short* __restrict__ Bt,
                                               void* __restrict__ Cout,
                                               unsigned short* __restrict__ Vt,
                                               int M, int N, int K, int lda, int ldc,
                                               int nbx) {
    static_assert(!VT || NBF == 4, "VT path requires NBF=4");
    __shared__ __align__(16) unsigned short Au[128 * BKT];
    __shared__ __align__(16) unsigned short Bs[NBF * 32 * BKT];
    const int tid = threadIdx.x;
    const int w = tid >> 6;
    const int lane = tid & 63;

    const int nwg = gridDim.x;
    const int q8 = nwg >> 3;
    const int orig = blockIdx.x;
    const int newlin = (orig & 7) * q8 + (orig >> 3);
    const int by = newlin / nbx;
    const int bx = newlin - by * nbx;
    const int m0 = by * 128;
    const int n0 = bx * (NBF * 32);
    const int wr = w >> 1, wc = w & 1;

    f32x4 acc[4][NBF];
#pragma unroll
    for (int i = 0; i < 4; ++i)
#pragma unroll
        for (int j = 0; j < NBF; ++j) acc[i][j] = f32x4{0.f, 0.f, 0.f, 0.f};

    constexpr int CPR = BKT / 8;        // 16B chunks per row
    constexpr int RP = 256 / CPR;       // rows covered per 256-thread pass
    const int srow = tid / CPR;         // row within pass
    const int sch = (tid % CPR) ^ (srow & 7);   // pre-swizzled source chunk

    const int fq = lane & 15, fg = lane >> 4;

    for (int kt = 0; kt < K; kt += BKT) {
#pragma unroll
        for (int p = 0; p < 128 / RP; ++p)
            gload_lds16(A + (size_t)(m0 + p * RP + srow) * lda + kt + sch * 8,
                        &Au[(p * 256 + w * 64) * 8]);
#pragma unroll
        for (int p = 0; p < NBF * 32 / RP; ++p)
            gload_lds16(Bt + (size_t)(n0 + p * RP + srow) * K + kt + sch * 8,
                        &Bs[(p * 256 + w * 64) * 8]);
        __syncthreads();

        bf16x8 af[4], bfr[NBF];
#pragma unroll
        for (int sub = 0; sub < BKT / 32; ++sub) {
            const int xa = (((sub * 4 + fg) ^ (fq & 7)) << 3);
#pragma unroll
            for (int m = 0; m < 4; ++m)
                af[m] = *(const bf16x8*)&Au[(wr * 64 + m * 16 + fq) * BKT + xa];
#pragma unroll
            for (int n = 0; n < NBF; ++n)
                bfr[n] = *(const bf16x8*)&Bs[(wc * (NBF * 16) + n * 16 + fq) * BKT + xa];
#pragma unroll
            for (int m = 0; m < 4; ++m)
#pragma unroll
                for (int n = 0; n < NBF; ++n)
                    acc[m][n] = __builtin_amdgcn_mfma_f32_16x16x32_bf16(af[m], bfr[n], acc[m][n], 0, 0, 0);
        }
        __syncthreads();
    }

    const int crow = (lane >> 4) * 4;
    const int ccol = lane & 15;

    if constexpr (VT) {
        if (n0 >= 2048) {
            __shared__ __align__(16) unsigned short Tw[4][32 * 72];
            const int bb = m0 >> 11;
            const int h = ((n0 - 2048) >> 6) + wc;
            const int kvbase = (m0 & 2047) + wr * 64;
            unsigned short* vdst = Vt + (size_t)((bb * 16 + h) * 64) * 2048 + kvbase;
#pragma unroll
            for (int pass = 0; pass < 2; ++pass) {
#pragma unroll
                for (int m = 0; m < 4; ++m)
#pragma unroll
                    for (int nn = 0; nn < 2; ++nn) {
                        int n = pass * 2 + nn;
                        int c = nn * 16 + ccol;
                        *(ushort4*)&Tw[w][c * 72 + m * 16 + crow] =
                            pack4bf(acc[m][n][0], acc[m][n][1], acc[m][n][2], acc[m][n][3]);
                    }
                asm volatile("" ::: "memory");
                const int d_loc = lane >> 1;
                const int kvh = (lane & 1) * 32;
                unsigned short* dst = vdst + (size_t)(pass * 32 + d_loc) * 2048 + kvh;
#pragma unroll
                for (int i = 0; i < 4; ++i) {
                    bf16x8 v = *(const bf16x8*)&Tw[w][d_loc * 72 + kvh + i * 8];
                    *(bf16x8*)&dst[i * 8] = v;
                }
                asm volatile("" ::: "memory");
            }
            return;
        }
    }

#pragma unroll
    for (int m = 0; m < 4; ++m) {
#pragma unroll
        for (int n = 0; n < NBF; ++n) {
            int r0 = m0 + wr * 64 + m * 16 + crow;
            int c0 = n0 + wc * (NBF * 16) + n * 16 + ccol;
#pragma unroll
            for (int j = 0; j < 4; ++j) {
                if (OUTBF)
                    ((unsigned short*)Cout)[(size_t)(r0 + j) * ldc + c0] = f2bf(acc[m][n][j]);
                else
                    ((float*)Cout)[(size_t)(r0 + j) * ldc + c0] = acc[m][n][j];
            }
        }
    }
}

// ---------- causal flash attention (rotated pipeline, ping-pong unroll) ----------
// QKV fused [B*L, 3072] bf16: Q cols [0,1024), K [1024,2048).
// Vt [bh][d=64][kv=2048]. Q pre-scaled by log2(e)/sqrt(hd). O in-place over Q.
// Grid (32 bh, 32 y): linear%8 = bh%8; y -> qblk 31-y (heavy-first, measured).
// K/V^T staged via global_load_lds, XOR-pre-swizzled source (c^=row&7);
// reads x0/x1 same XOR -> conflict-free.
// Rotated pipeline with 2x PING-PONG UNROLL (no sprev=snew copies).
// Diagonal masking only in the (parity-branched) epilogue SM.
__global__ __launch_bounds__(256) void flash_kernel(unsigned short* __restrict__ QKV,
                                                    const unsigned short* __restrict__ Vt) {
    __shared__ __align__(16) unsigned short Ks[2][64 * 64];
    __shared__ __align__(16) unsigned short Vs[64 * 64];
    __shared__ __align__(16) unsigned short Ps[4][16 * 72];

    const int tid = threadIdx.x;
    const int w = tid >> 6;
    const int lane = tid & 63;
    const int bh = blockIdx.x;          // XCD = bh % 8
    const int b = bh >> 4, h = bh & 15;
    const int rowbase = b * 2048;
    const int hd0 = h * 64;
    const int S = 3072;

    const int qi = lane & 15;           // lane's q column (softmax space)
    const int g = lane >> 4;            // lane group
    const int x0 = ((g ^ (qi & 7)) << 3);
    const int x1 = (((g ^ 4) ^ (qi & 7)) << 3);

    const int qblk = (31 - (int)blockIdx.y) * 64;
    const int q0 = qblk + w * 16;
    const int nt = qblk / 64 + 1;
    const int q_rel = w * 16 + qi;

    const unsigned short* gK[2];
    const unsigned short* gV[2];
#pragma unroll
    for (int p = 0; p < 2; ++p) {
        int row = p * 32 + w * 8 + (lane >> 3);       // kv for K, d for V
        int ch = (lane & 7) ^ (row & 7);
        gK[p] = QKV + (size_t)(rowbase + row) * S + 1024 + hd0 + ch * 8;
        gV[p] = Vt + (size_t)(bh * 64 + row) * 2048 + ch * 8;
    }

#define STAGE_K(buf)                                            \
    do {                                                        \
        gload_lds16(gK[0], &Ks[buf][w * 512]);                  \
        gload_lds16(gK[1], &Ks[buf][2048 + w * 512]);           \
        gK[0] += 64 * S; gK[1] += 64 * S;                       \
    } while (0)
#define STAGE_V()                                               \
    do {                                                        \
        gload_lds16(gV[0], &Vs[w * 512]);                       \
        gload_lds16(gV[1], &Vs[2048 + w * 512]);                \
        gV[0] += 64; gV[1] += 64;                               \
    } while (0)

    bf16x8 qf[2];
#pragma unroll
    for (int st = 0; st < 2; ++st)
        qf[st] = *(const bf16x8*)(QKV + (size_t)(rowbase + q0 + qi) * S + hd0 +
                                  st * 32 + g * 8);

    float m_prev = -1e30f, lsum = 0.f;   // per-lane partials (16 kv cols)
    f32x4 oacc[4];
#pragma unroll
    for (int n = 0; n < 4; ++n) oacc[n] = f32x4{0.f, 0.f, 0.f, 0.f};
    f32x4 sA[4], sB[4];

    STAGE_K(0);
    if (nt > 1) STAGE_K(1);
    __syncthreads();   // drains K(0), K(1)

    // QKT of tile (reads Ks[KB]) into SP
#define QKT(SP, KB)                                                            \
    do {                                                                       \
        const unsigned short* Kc = Ks[KB];                                     \
        __builtin_amdgcn_s_setprio(1);                                         \
        _Pragma("unroll")                                                      \
        for (int n = 0; n < 4; ++n) {                                          \
            bf16x8 k0 = *(const bf16x8*)&Kc[(n * 16 + qi) * 64 + x0];          \
            bf16x8 k1 = *(const bf16x8*)&Kc[(n * 16 + qi) * 64 + x1];          \
            f32x4 c = f32x4{0.f, 0.f, 0.f, 0.f};                               \
            c = __builtin_amdgcn_mfma_f32_16x16x32_bf16(k0, qf[0], c, 0, 0, 0);\
            c = __builtin_amdgcn_mfma_f32_16x16x32_bf16(k1, qf[1], c, 0, 0, 0);\
            SP[n] = c;                                                         \
        }                                                                      \
        __builtin_amdgcn_s_setprio(0);                                         \
    } while (0)

    // softmax on SP (no masking) -> Ps, lsum, oacc rescale
#define SOFTMAX(SP)                                                            \
    do {                                                                       \
        float tmax = m_prev;                                                   \
        _Pragma("unroll")                                                      \
        for (int n = 0; n < 4; ++n) {                                          \
            tmax = fmaxf(fmaxf(tmax, SP[n][0]), SP[n][1]);                     \
            tmax = fmaxf(fmaxf(tmax, SP[n][2]), SP[n][3]);                     \
        }                                                                      \
        const bool defer = __all(tmax - m_prev <= 8.0f);                       \
        float mcur = m_prev;                                                   \
        if (!defer) {                                                          \
            tmax = fmaxf(tmax, __shfl_xor(tmax, 16));                          \
            tmax = fmaxf(tmax, __shfl_xor(tmax, 32));                          \
            mcur = tmax;                                                       \
            float alpha = EXP2(m_prev - mcur);                                 \
            lsum *= alpha;                                                     \
            _Pragma("unroll")                                                  \
            for (int n = 0; n < 4; ++n)                                        \
                _Pragma("unroll")                                              \
                for (int j = 0; j < 4; ++j) oacc[n][j] *= alpha;               \
            m_prev = mcur;                                                     \
        }                                                                      \
        float psum = 0.f;                                                      \
        _Pragma("unroll")                                                      \
        for (int n = 0; n < 4; ++n) {                                          \
            float p0 = EXP2(SP[n][0] - mcur);                                  \
            float p1 = EXP2(SP[n][1] - mcur);                                  \
            float p2 = EXP2(SP[n][2] - mcur);                                  \
            float p3 = EXP2(SP[n][3] - mcur);                                  \
            psum += (p0 + p1) + (p2 + p3);                                     \
            *(ushort4*)&Ps[w][qi * 72 + n * 16 + g * 4] = pack4bf(p0, p1, p2, p3); \
        }                                                                      \
        lsum += psum;                                                          \
    } while (0)

#define PV_STEP()                                                              \
    do {                                                                       \
        __builtin_amdgcn_s_setprio(1);                                         \
        _Pragma("unroll")                                                      \
        for (int st = 0; st < 2; ++st) {                                       \
            bf16x8 ptf = *(const bf16x8*)&Ps[w][qi * 72 + st * 32 + g * 8];    \
            const int xo = st ? x1 : x0;                                       \
            _Pragma("unroll")                                                  \
            for (int n = 0; n < 4; ++n) {                                      \
                bf16x8 vfr = *(const bf16x8*)&Vs[(n * 16 + qi) * 64 + xo];     \
                oacc[n] = __builtin_amdgcn_mfma_f32_16x16x32_bf16(vfr, ptf, oacc[n], 0, 0, 0); \
            }                                                                  \
        }                                                                      \
        __builtin_amdgcn_s_setprio(0);                                         \
    } while (0)

    // full iteration for tile T>0: QKT(T)->SNEW, SM+PV of tile T-1 on SOLD
#define ITER(T, SNEW, SOLD, KB)                                                \
    do {                                                                       \
        QKT(SNEW, KB);                                                         \
        SOFTMAX(SOLD);                                                         \
        __syncthreads();  /* barA: V(T-1) landed */                            \
        PV_STEP();        /* PV(T-1) on Vs */                                  \
        __syncthreads();  /* barB: Vs reads done */                            \
        STAGE_V();        /* V(T) -> Vs */                                     \
        if ((T) + 2 < nt) STAGE_K(KB);                                         \
    } while (0)

    // ---- tile 0 (no SM/PV yet): t even -> sA ----
    QKT(sA, 0);
    __syncthreads();                 // barA (uniform barrier count)
    __syncthreads();                 // barB: QKT(0) reads retired before DMA
    STAGE_V();                       // V(0)
    if (2 < nt) STAGE_K(0);          // K(2)

    // ---- ping-pong pairs: t odd uses (sB <- QKT, SM on sA), t even mirrored ----
    int t = 1;
    for (; t + 1 < nt; t += 2) {
        ITER(t, sB, sA, 1);
        ITER(t + 1, sA, sB, 0);
    }
    if (t < nt) ITER(t, sB, sA, 1);  // leftover t is odd

    // ---- epilogue: diagonal masking + SM + PV for tile nt-1 (parity branch) ----
    __syncthreads();   // drains V(nt-1)
    if ((nt - 1) & 1) {
#pragma unroll
        for (int n = 0; n < 4; ++n)
#pragma unroll
            for (int j = 0; j < 4; ++j)
                if (n * 16 + g * 4 + j > q_rel) sB[n][j] = -1e30f;
        SOFTMAX(sB);
    } else {
#pragma unroll
        for (int n = 0; n < 4; ++n)
#pragma unroll
            for (int j = 0; j < 4; ++j)
                if (n * 16 + g * 4 + j > q_rel) sA[n][j] = -1e30f;
        SOFTMAX(sA);
    }
    asm volatile("" ::: "memory");
    PV_STEP();
#undef QKT
#undef SOFTMAX
#undef PV_STEP
#undef ITER
#undef STAGE_K
#undef STAGE_V

    // ---- reduce lsum across the column group, normalize, write O ----
    {
        lsum += __shfl_xor(lsum, 16);
        lsum += __shfl_xor(lsum, 32);
        float inv = 1.0f / lsum;
#pragma unroll
        for (int n = 0; n < 4; ++n)
            *(ushort4*)&Ps[w][qi * 72 + n * 16 + g * 4] =
                pack4bf(oacc[n][0] * inv, oacc[n][1] * inv, oacc[n][2] * inv, oacc[n][3] * inv);
        asm volatile("" ::: "memory");
        const int r = lane >> 2;
        const int cs = (lane & 3) * 16;
        bf16x8 o0 = *(const bf16x8*)&Ps[w][r * 72 + cs];
        bf16x8 o1 = *(const bf16x8*)&Ps[w][r * 72 + cs + 8];
        *(bf16x8*)&QKV[(size_t)(rowbase + q0 + r) * S + hd0 + cs] = o0;
        *(bf16x8*)&QKV[(size_t)(rowbase + q0 + r) * S + hd0 + cs + 8] = o1;
    }
}

// ---------- launch ----------
extern "C" void kernel_launch(void* const* d_in, const int* in_sizes, int n_in,
                              void* d_out, int out_size, void* d_ws, size_t ws_size,
                              hipStream_t stream) {
    const float* x  = (const float*)d_in[0];
    const float* Wq = (const float*)d_in[1];
    const float* Wk = (const float*)d_in[2];
    const float* Wv = (const float*)d_in[3];
    const float* Wo = (const float*)d_in[4];
    float* out = (float*)d_out;

    const int WN = 1024 * 1024;
    const int XN = 4096 * 1024;

    // ws (32MB): Wqkv_t (6MB) + Wo_t (2MB) + QKV [4096][3072] (24MB).
    // d_out (16MB) doubles as scratch: [Xbf 8MB][Vt 8MB] — both dead before the
    // final O-projection overwrites d_out. Deterministic across replays.
    unsigned short* ws   = (unsigned short*)d_ws;
    unsigned short* Wqkv = ws;
    unsigned short* Wot  = Wqkv + 3 * WN;
    unsigned short* QKV  = Wot + WN;
    unsigned short* Xbf  = (unsigned short*)d_out;
    unsigned short* Vt   = Xbf + XN;

    // fused prologue: x cast + weight transposes (Q scale folds 1/sqrt(hd)*log2e)
    prologue_kernel<<<5120, 256, 0, stream>>>(
        x, Xbf, Wq, Wk, Wv, Wo,
        Wqkv, Wqkv + WN, Wqkv + 2 * WN, Wot, 0.125f * 1.4426950408889634f);

    // fused QKV projection: [4096,1024] x [1024,3072] -> [4096,3072];
    // V-blocks write transposed into Vt (fused vtrans). BK=64 (3 blocks/CU).
    gemm_bt<1, 1, 4, 64><<<24 * 32, 256, 0, stream>>>(
        Xbf, Wqkv, QKV, Vt, 4096, 3072, 1024, 1024, 3072, 24);

    flash_kernel<<<dim3(32, 32), 256, 0, stream>>>(QKV, Vt);

    // output projection: A = O (bf16, Q region of QKV, lda=3072), BN=64,
    // BK=128 (halved barriers; grid-capped 2 blocks/CU so no occupancy cost).
    gemm_bt<0, 0, 2, 128><<<16 * 32, 256, 0, stream>>>(
        QKV, Wot, out, nullptr, 4096, 1024, 1024, 3072, 1024, 16);
}